// Round 6
// baseline (71.732 us; speedup 1.0000x reference)
//
#include <hip/hip_runtime.h>
#include <hip/hip_bf16.h>
#include <cstdint>

#define EPS 1e-5f

typedef short bf16x8 __attribute__((ext_vector_type(8)));
typedef float f32x16 __attribute__((ext_vector_type(16)));
typedef unsigned int u32x4 __attribute__((ext_vector_type(4)));

// ws float-offsets
#define WS_TW1S 0       // 16384 ushort: K-slot-permuted fragment layout (chi mapping)
#define WS_FW   8192    // 8192 ushort: [hc*128 + k]
#define WS_TB1Q 12288   // 256 floats: [(t*2+hi)*16 + q]
#define WS_W2Q  12544   // 256 floats: [(t*2+hi)*16 + q]
#define WS_FBQ  12800   // 64 floats:  [hi*32 + ht*16 + q]
#define WS_C2   12864   // 8 floats

static __device__ __forceinline__ unsigned short f2bf(float f) {
    unsigned int u = __float_as_uint(f);
    u += 0x7fffu + ((u >> 16) & 1u);   // RNE
    return (unsigned short)(u >> 16);
}
static __device__ __forceinline__ unsigned pk_bf16(float lo, float hi) {
    unsigned l = (unsigned)(unsigned short)__builtin_bit_cast(unsigned short, __float2bfloat16(lo));
    unsigned h = (unsigned)(unsigned short)__builtin_bit_cast(unsigned short, __float2bfloat16(hi));
    return l | (h << 16);
}
static __device__ __forceinline__ short f2bf_fast(float f) {
    __hip_bfloat16 b = __float2bfloat16(f);
    return __builtin_bit_cast(short, b);
}

// Fold both eval-mode BNs; emit bf16 weights + fragment-ordered bias tables.
// chi: channel j = ht*32+qq*8+4h+m -> ks = ht*2+(qq>>1), slot = 8h+(qq&1)*4+m
__global__ void tarnet_pre(
    const float* __restrict__ fw, const float* __restrict__ fb,
    const float* __restrict__ f_gamma, const float* __restrict__ f_beta,
    const float* __restrict__ f_mean,  const float* __restrict__ f_var,
    const float* __restrict__ tw1, const float* __restrict__ tb1,
    const float* __restrict__ t_gamma, const float* __restrict__ t_beta,
    const float* __restrict__ t_mean,  const float* __restrict__ t_var,
    const float* __restrict__ tw2, const float* __restrict__ tb2,
    float* __restrict__ ws)
{
    __shared__ float fs[64], fsh[64];
    const int i = threadIdx.x;  // 256 threads
    if (i < 64) {
        float s = f_gamma[i] * rsqrtf(f_var[i] + EPS);
        fs[i]  = s;
        fsh[i] = f_beta[i] - f_mean[i] * s;
    }
    __syncthreads();

    unsigned short* tw1s_u = (unsigned short*)(ws + WS_TW1S);
    unsigned short* fw_u   = (unsigned short*)(ws + WS_FW);

    const int t = i >> 5, r = i & 31;
    const int idx = t * 32 + r;
    {
        float tsc  = t_gamma[idx] * rsqrtf(t_var[idx] + EPS);
        float w2s  = tw2[idx] * tsc;
        float tb1s = tb1[idx];
        for (int j = 0; j < 64; ++j) {
            float w = tw1[idx * 64 + j];
            tb1s += w * fsh[j];
            int ht = j >> 5, qq = (j >> 3) & 3, h = (j >> 2) & 1, m = j & 3;
            int ks = ht * 2 + (qq >> 1);
            int ep = (qq & 1) * 4 + m;
            tw1s_u[(((t*4 + ks)*2 + h)*32 + r)*8 + ep] = f2bf(w * fs[j]);
        }
        int q  = ((r >> 3) << 2) | (r & 3);
        int hq = (r >> 2) & 1;
        ws[WS_TB1Q + (t*2 + hq)*16 + q] = tb1s;
        ws[WS_W2Q  + (t*2 + hq)*16 + q] = w2s;
    }
    if (r == 0) {
        float a = tb2[t];
        for (int rr = 0; rr < 32; ++rr) {
            int id2 = t*32 + rr;
            float ts2 = t_gamma[id2] * rsqrtf(t_var[id2] + EPS);
            a += tw2[id2] * (t_beta[id2] - ts2 * t_mean[id2]);
        }
        ws[WS_C2 + t] = a;
    }
    if (i < 64) {  // i = hc
        for (int k = 0; k < 128; ++k) fw_u[i*128 + k] = f2bf(fw[i*128 + k]);
        int ht = i >> 5, r32 = i & 31;
        int q  = ((r32 >> 3) << 2) | (r32 & 3);
        int hq = (r32 >> 2) & 1;
        ws[WS_FBQ + hq*32 + ht*16 + q] = fb[i];
    }
}

// 4 waves/block, 32 samples/wave. No LDS/barriers. VGPR<=128 -> 4 waves/SIMD.
__global__ __launch_bounds__(256, 4) void tarnet_main(
    const float* __restrict__ x, const int* __restrict__ t_arr,
    const float* __restrict__ ws, float* __restrict__ out)
{
    const int tid  = threadIdx.x;
    const int wave = tid >> 6, lane = tid & 63;
    const int ln31 = lane & 31, hi = lane >> 5;
    const int sample = blockIdx.x * 128 + wave * 32 + ln31;

    const unsigned short* fw_u   = (const unsigned short*)(ws + WS_FW);
    const unsigned short* tw1s_u = (const unsigned short*)(ws + WS_TW1S);

    const int tsel = t_arr[sample];

    // ---- hoist ALL x loads: 16 independent global_load_dwordx4 in flight ----
    float4 xr[16];
    const float4* xp = (const float4*)x + (size_t)sample * 32 + hi * 2;
#pragma unroll
    for (int ks = 0; ks < 8; ++ks) {
        xr[2*ks]   = xp[ks*4];
        xr[2*ks+1] = xp[ks*4 + 1];
    }

    // ---- GEMM1: h^T = fw @ x^T (+fb), rows=hc, cols=samples ----
    f32x16 acc[2];   // [ht]
    {
        const float4* fbq4 = (const float4*)(ws + WS_FBQ);
#pragma unroll
        for (int i2 = 0; i2 < 8; ++i2) {
            float4 v = fbq4[hi*8 + i2];
            const int ht = i2 >> 2, qb = (i2 & 3) * 4;
            acc[ht][qb+0] = v.x; acc[ht][qb+1] = v.y;
            acc[ht][qb+2] = v.z; acc[ht][qb+3] = v.w;
        }
    }
#pragma unroll
    for (int ks = 0; ks < 8; ++ks) {
        bf16x8 wa0 = *(const bf16x8*)(fw_u + (ln31     )*128 + ks*16 + hi*8);
        bf16x8 wa1 = *(const bf16x8*)(fw_u + (ln31 + 32)*128 + ks*16 + hi*8);
        float4 xa = xr[2*ks], xb = xr[2*ks+1];
        bf16x8 xf;   // B-frag: cols = samples
        xf[0] = f2bf_fast(xa.x); xf[1] = f2bf_fast(xa.y);
        xf[2] = f2bf_fast(xa.z); xf[3] = f2bf_fast(xa.w);
        xf[4] = f2bf_fast(xb.x); xf[5] = f2bf_fast(xb.y);
        xf[6] = f2bf_fast(xb.z); xf[7] = f2bf_fast(xb.w);
        acc[0] = __builtin_amdgcn_mfma_f32_32x32x16_bf16(wa0, xf, acc[0], 0, 0, 0);
        acc[1] = __builtin_amdgcn_mfma_f32_32x32x16_bf16(wa1, xf, acc[1], 0, 0, 0);
    }

    // ---- relu -> bf16 pack: lane-local B-frags under chi ----
    bf16x8 hb[4];
    {
        unsigned w0[2][4], w1[2][4];
#pragma unroll
        for (int ht = 0; ht < 2; ++ht)
#pragma unroll
            for (int qq = 0; qq < 4; ++qq) {
                float a0 = fmaxf(acc[ht][qq*4+0], 0.f);
                float a1 = fmaxf(acc[ht][qq*4+1], 0.f);
                float a2 = fmaxf(acc[ht][qq*4+2], 0.f);
                float a3 = fmaxf(acc[ht][qq*4+3], 0.f);
                w0[ht][qq] = pk_bf16(a0, a1);
                w1[ht][qq] = pk_bf16(a2, a3);
            }
#pragma unroll
        for (int ks = 0; ks < 4; ++ks) {
            const int ht = ks >> 1, qa = (ks & 1) * 2;
            u32x4 wv = {w0[ht][qa], w1[ht][qa], w0[ht][qa+1], w1[ht][qa+1]};
            hb[ks] = __builtin_bit_cast(bf16x8, wv);
        }
    }

    // ---- GEMM2 dense over 8 heads: z = tw1s[th] @ h, rows=r, cols=samples ----
    float outv = 0.f;
#pragma unroll 2
    for (int th = 0; th < 8; ++th) {
        bf16x8 aw[4];
#pragma unroll
        for (int ks = 0; ks < 4; ++ks)
            aw[ks] = *(const bf16x8*)(tw1s_u + (((th*4 + ks)*2 + hi)*32 + ln31)*8);
        float4 tb4[4], w24[4];
#pragma unroll
        for (int i2 = 0; i2 < 4; ++i2) {
            tb4[i2] = ((const float4*)(ws + WS_TB1Q))[(th*2 + hi)*4 + i2];
            w24[i2] = ((const float4*)(ws + WS_W2Q))[(th*2 + hi)*4 + i2];
        }
        const float c2t = ws[WS_C2 + th];
        f32x16 z;
#pragma unroll
        for (int q = 0; q < 16; ++q) z[q] = ((const float*)tb4)[q];  // tb1s C-init
        z = __builtin_amdgcn_mfma_f32_32x32x16_bf16(aw[0], hb[0], z, 0, 0, 0);
        z = __builtin_amdgcn_mfma_f32_32x32x16_bf16(aw[1], hb[1], z, 0, 0, 0);
        z = __builtin_amdgcn_mfma_f32_32x32x16_bf16(aw[2], hb[2], z, 0, 0, 0);
        z = __builtin_amdgcn_mfma_f32_32x32x16_bf16(aw[3], hb[3], z, 0, 0, 0);
        float p = 0.f;
#pragma unroll
        for (int q = 0; q < 16; ++q)
            p = fmaf(((const float*)w24)[q], fmaxf(z[q], 0.f), p);
        p += __shfl_xor(p, 32);   // other r-half
        p += c2t;
        outv = (th == tsel) ? p : outv;
    }
    if (!hi) out[sample] = outv;   // coalesced 32-lane store
}

extern "C" void kernel_launch(void* const* d_in, const int* in_sizes, int n_in,
                              void* d_out, int out_size, void* d_ws, size_t ws_size,
                              hipStream_t stream) {
    const float* x       = (const float*)d_in[0];
    const int*   t       = (const int*)  d_in[1];
    const float* fw      = (const float*)d_in[2];
    const float* fb      = (const float*)d_in[3];
    const float* f_gamma = (const float*)d_in[4];
    const float* f_beta  = (const float*)d_in[5];
    const float* f_mean  = (const float*)d_in[6];
    const float* f_var   = (const float*)d_in[7];
    const float* tw1     = (const float*)d_in[8];
    const float* tb1     = (const float*)d_in[9];
    const float* t_gamma = (const float*)d_in[10];
    const float* t_beta  = (const float*)d_in[11];
    const float* t_mean  = (const float*)d_in[12];
    const float* t_var   = (const float*)d_in[13];
    const float* tw2     = (const float*)d_in[14];
    const float* tb2     = (const float*)d_in[15];

    float* ws   = (float*)d_ws;
    float* outp = (float*)d_out;
    const int B = in_sizes[0] / 128;   // 262144

    tarnet_pre<<<1, 256, 0, stream>>>(fw, fb, f_gamma, f_beta, f_mean, f_var,
                                      tw1, tb1, t_gamma, t_beta, t_mean, t_var,
                                      tw2, tb2, ws);
    tarnet_main<<<B / 128, 256, 0, stream>>>(x, t, ws, outp);
}

// Round 7
// 63.152 us; speedup vs baseline: 1.1359x; 1.1359x over previous
//
#include <hip/hip_runtime.h>
#include <hip/hip_bf16.h>
#include <cstdint>

#define EPS 1e-5f

typedef short bf16x8 __attribute__((ext_vector_type(8)));
typedef float f32x16 __attribute__((ext_vector_type(16)));
typedef unsigned int u32x4 __attribute__((ext_vector_type(4)));

// ws float-offsets — ONE contiguous 12872-float block, mirrored into LDS.
#define WS_TW1S 0       // 16384 ushort: chi-permuted GEMM2 A-frag layout
#define WS_FWQ  8192    // 8192 ushort: GEMM1 A-frag layout [((ks*2+h)*64 + hc)*8 + jj]
#define WS_TB1Q 12288   // 256 floats: [(t*2+hi)*16 + q]
#define WS_W2Q  12544   // 256 floats: [(t*2+hi)*16 + q]
#define WS_FBQ  12800   // 64 floats:  [hi*32 + ht*16 + q]
#define WS_C2   12864   // 8 floats
#define WS_TOTAL 12872  // floats (= 3218 uint4)

static __device__ __forceinline__ unsigned short f2bf(float f) {
    unsigned int u = __float_as_uint(f);
    u += 0x7fffu + ((u >> 16) & 1u);   // RNE
    return (unsigned short)(u >> 16);
}
static __device__ __forceinline__ unsigned pk_bf16(float lo, float hi) {
    unsigned l = (unsigned)(unsigned short)__builtin_bit_cast(unsigned short, __float2bfloat16(lo));
    unsigned h = (unsigned)(unsigned short)__builtin_bit_cast(unsigned short, __float2bfloat16(hi));
    return l | (h << 16);
}
static __device__ __forceinline__ short f2bf_fast(float f) {
    __hip_bfloat16 b = __float2bfloat16(f);
    return __builtin_bit_cast(short, b);
}

// Fold both eval-mode BNs; emit bf16 weights in frag-native layouts.
// chi: channel j = ht*32+qq*8+4h+m -> ks = ht*2+(qq>>1), slot = 8h+(qq&1)*4+m
__global__ void tarnet_pre(
    const float* __restrict__ fw, const float* __restrict__ fb,
    const float* __restrict__ f_gamma, const float* __restrict__ f_beta,
    const float* __restrict__ f_mean,  const float* __restrict__ f_var,
    const float* __restrict__ tw1, const float* __restrict__ tb1,
    const float* __restrict__ t_gamma, const float* __restrict__ t_beta,
    const float* __restrict__ t_mean,  const float* __restrict__ t_var,
    const float* __restrict__ tw2, const float* __restrict__ tb2,
    float* __restrict__ ws)
{
    __shared__ float fs[64], fsh[64];
    const int i = threadIdx.x;  // 256 threads
    if (i < 64) {
        float s = f_gamma[i] * rsqrtf(f_var[i] + EPS);
        fs[i]  = s;
        fsh[i] = f_beta[i] - f_mean[i] * s;
    }
    __syncthreads();

    unsigned short* tw1s_u = (unsigned short*)(ws + WS_TW1S);
    unsigned short* fwq_u  = (unsigned short*)(ws + WS_FWQ);

    const int t = i >> 5, r = i & 31;
    const int idx = t * 32 + r;
    {
        float tsc  = t_gamma[idx] * rsqrtf(t_var[idx] + EPS);
        float w2s  = tw2[idx] * tsc;
        float tb1s = tb1[idx];
        for (int j = 0; j < 64; ++j) {
            float w = tw1[idx * 64 + j];
            tb1s += w * fsh[j];
            int ht = j >> 5, qq = (j >> 3) & 3, h = (j >> 2) & 1, m = j & 3;
            int ks = ht * 2 + (qq >> 1);
            int ep = (qq & 1) * 4 + m;
            tw1s_u[(((t*4 + ks)*2 + h)*32 + r)*8 + ep] = f2bf(w * fs[j]);
        }
        int q  = ((r >> 3) << 2) | (r & 3);
        int hq = (r >> 2) & 1;
        ws[WS_TB1Q + (t*2 + hq)*16 + q] = tb1s;
        ws[WS_W2Q  + (t*2 + hq)*16 + q] = w2s;
    }
    if (r == 0) {
        float a = tb2[t];
        for (int rr = 0; rr < 32; ++rr) {
            int id2 = t*32 + rr;
            float ts2 = t_gamma[id2] * rsqrtf(t_var[id2] + EPS);
            a += tw2[id2] * (t_beta[id2] - ts2 * t_mean[id2]);
        }
        ws[WS_C2 + t] = a;
    }
    if (i < 64) {  // i = hc: GEMM1 A-frag layout
        for (int k = 0; k < 128; ++k) {
            int ks = k >> 4, h = (k >> 3) & 1, jj = k & 7;
            fwq_u[(((ks*2 + h)*64) + i)*8 + jj] = f2bf(fw[i*128 + k]);
        }
        int ht = i >> 5, r32 = i & 31;
        int q  = ((r32 >> 3) << 2) | (r32 & 3);
        int hq = (r32 >> 2) & 1;
        ws[WS_FBQ + hq*32 + ht*16 + q] = fb[i];
    }
}

// 4 waves/block, 64 samples/wave; weights in LDS; x deep-pipelined from global.
__global__ __launch_bounds__(256, 2) void tarnet_main(
    const float* __restrict__ x, const int* __restrict__ t_arr,
    const float* __restrict__ ws, float* __restrict__ out)
{
    __shared__ float smem[WS_TOTAL];   // 51.5 KB, mirrors ws block
    {
        const uint4* src = (const uint4*)ws;
        uint4* dst = (uint4*)smem;
        for (int k = threadIdx.x; k < WS_TOTAL / 4; k += 256) dst[k] = src[k];
    }
    __syncthreads();

    const unsigned short* s_tw1s = (const unsigned short*)smem;
    const unsigned short* s_fwq  = (const unsigned short*)(smem + WS_FWQ);
    const float* s_tb1q = smem + WS_TB1Q;
    const float* s_w2q  = smem + WS_W2Q;
    const float* s_fbq  = smem + WS_FBQ;
    const float* s_c2   = smem + WS_C2;

    const int tid  = threadIdx.x;
    const int wave = tid >> 6, lane = tid & 63;
    const int ln31 = lane & 31, hi = lane >> 5;
    const int sbase = blockIdx.x * 256 + wave * 64;

    const int tsel0 = t_arr[sbase + ln31];
    const int tsel1 = t_arr[sbase + 32 + ln31];

    // ---- x: issue all 32 dwordx4 loads, convert to bf16 as they land ----
    float4 xr[32];
    {
        const float4* xq0 = (const float4*)x + (size_t)(sbase + ln31) * 32 + hi * 2;
        const float4* xq1 = (const float4*)x + (size_t)(sbase + 32 + ln31) * 32 + hi * 2;
#pragma unroll
        for (int ks = 0; ks < 8; ++ks) {
            xr[2*ks]      = xq0[ks*4];
            xr[2*ks+1]    = xq0[ks*4 + 1];
            xr[16+2*ks]   = xq1[ks*4];
            xr[16+2*ks+1] = xq1[ks*4 + 1];
        }
    }
    bf16x8 xb[16];   // [st*8 + ks]
#pragma unroll
    for (int i2 = 0; i2 < 16; ++i2) {
        float4 xa = xr[2*i2], xc = xr[2*i2+1];
        bf16x8 v;
        v[0] = f2bf_fast(xa.x); v[1] = f2bf_fast(xa.y);
        v[2] = f2bf_fast(xa.z); v[3] = f2bf_fast(xa.w);
        v[4] = f2bf_fast(xc.x); v[5] = f2bf_fast(xc.y);
        v[6] = f2bf_fast(xc.z); v[7] = f2bf_fast(xc.w);
        xb[i2] = v;
    }

    // ---- GEMM1: h^T = fw @ x^T (+fb), rows=hc, cols=samples ----
    f32x16 acc[2][2];   // [st][ht]
    {
#pragma unroll
        for (int ht = 0; ht < 2; ++ht)
#pragma unroll
            for (int q = 0; q < 16; ++q) {
                float v = s_fbq[hi*32 + ht*16 + q];
                acc[0][ht][q] = v;
                acc[1][ht][q] = v;
            }
    }
#pragma unroll
    for (int ks = 0; ks < 8; ++ks) {
        // A-frags from LDS, lane-consecutive 16B -> conflict-free b128
        bf16x8 wa0 = *(const bf16x8*)(s_fwq + (((ks*2 + hi)*64) + ln31     )*8);
        bf16x8 wa1 = *(const bf16x8*)(s_fwq + (((ks*2 + hi)*64) + ln31 + 32)*8);
        acc[0][0] = __builtin_amdgcn_mfma_f32_32x32x16_bf16(wa0, xb[ks],   acc[0][0], 0, 0, 0);
        acc[0][1] = __builtin_amdgcn_mfma_f32_32x32x16_bf16(wa1, xb[ks],   acc[0][1], 0, 0, 0);
        acc[1][0] = __builtin_amdgcn_mfma_f32_32x32x16_bf16(wa0, xb[8+ks], acc[1][0], 0, 0, 0);
        acc[1][1] = __builtin_amdgcn_mfma_f32_32x32x16_bf16(wa1, xb[8+ks], acc[1][1], 0, 0, 0);
    }

    // ---- relu -> bf16 pack: lane-local B-frags under chi ----
    bf16x8 hb[2][4];   // [st][ks]
#pragma unroll
    for (int st = 0; st < 2; ++st) {
        unsigned w0[2][4], w1[2][4];
#pragma unroll
        for (int ht = 0; ht < 2; ++ht)
#pragma unroll
            for (int qq = 0; qq < 4; ++qq) {
                float a0 = fmaxf(acc[st][ht][qq*4+0], 0.f);
                float a1 = fmaxf(acc[st][ht][qq*4+1], 0.f);
                float a2 = fmaxf(acc[st][ht][qq*4+2], 0.f);
                float a3 = fmaxf(acc[st][ht][qq*4+3], 0.f);
                w0[ht][qq] = pk_bf16(a0, a1);
                w1[ht][qq] = pk_bf16(a2, a3);
            }
#pragma unroll
        for (int ks = 0; ks < 4; ++ks) {
            const int ht = ks >> 1, qa = (ks & 1) * 2;
            u32x4 wv = {w0[ht][qa], w1[ht][qa], w0[ht][qa+1], w1[ht][qa+1]};
            hb[st][ks] = __builtin_bit_cast(bf16x8, wv);
        }
    }

    // ---- GEMM2 dense over 8 heads: z = tw1s[th] @ h, rows=r, cols=samples ----
    float out0 = 0.f, out1 = 0.f;
#pragma unroll 2
    for (int th = 0; th < 8; ++th) {
        bf16x8 aw[4];
#pragma unroll
        for (int ks = 0; ks < 4; ++ks)
            aw[ks] = *(const bf16x8*)(s_tw1s + (((th*4 + ks)*2 + hi)*32 + ln31)*8);
        const float* tbq = s_tb1q + (th*2 + hi)*16;   // LDS broadcast
        const float* w2q = s_w2q  + (th*2 + hi)*16;
        const float c2t  = s_c2[th];
#pragma unroll
        for (int st = 0; st < 2; ++st) {
            f32x16 z;
#pragma unroll
            for (int q = 0; q < 16; ++q) z[q] = tbq[q];   // tb1s C-init
            z = __builtin_amdgcn_mfma_f32_32x32x16_bf16(aw[0], hb[st][0], z, 0, 0, 0);
            z = __builtin_amdgcn_mfma_f32_32x32x16_bf16(aw[1], hb[st][1], z, 0, 0, 0);
            z = __builtin_amdgcn_mfma_f32_32x32x16_bf16(aw[2], hb[st][2], z, 0, 0, 0);
            z = __builtin_amdgcn_mfma_f32_32x32x16_bf16(aw[3], hb[st][3], z, 0, 0, 0);
            // 4-acc tree reduce (depth ~4 fma + 2 add vs 16-fma chain)
            float p0 = 0.f, p1 = 0.f, p2 = 0.f, p3 = 0.f;
#pragma unroll
            for (int q = 0; q < 4; ++q) {
                p0 = fmaf(w2q[q],    fmaxf(z[q],    0.f), p0);
                p1 = fmaf(w2q[q+4],  fmaxf(z[q+4],  0.f), p1);
                p2 = fmaf(w2q[q+8],  fmaxf(z[q+8],  0.f), p2);
                p3 = fmaf(w2q[q+12], fmaxf(z[q+12], 0.f), p3);
            }
            float p = (p0 + p1) + (p2 + p3);
            p += __shfl_xor(p, 32);   // other r-half
            p += c2t;
            if (st == 0) out0 = (th == tsel0) ? p : out0;
            else         out1 = (th == tsel1) ? p : out1;
        }
    }
    out[sbase + lane] = hi ? out1 : out0;   // coalesced 64-lane store
}

extern "C" void kernel_launch(void* const* d_in, const int* in_sizes, int n_in,
                              void* d_out, int out_size, void* d_ws, size_t ws_size,
                              hipStream_t stream) {
    const float* x       = (const float*)d_in[0];
    const int*   t       = (const int*)  d_in[1];
    const float* fw      = (const float*)d_in[2];
    const float* fb      = (const float*)d_in[3];
    const float* f_gamma = (const float*)d_in[4];
    const float* f_beta  = (const float*)d_in[5];
    const float* f_mean  = (const float*)d_in[6];
    const float* f_var   = (const float*)d_in[7];
    const float* tw1     = (const float*)d_in[8];
    const float* tb1     = (const float*)d_in[9];
    const float* t_gamma = (const float*)d_in[10];
    const float* t_beta  = (const float*)d_in[11];
    const float* t_mean  = (const float*)d_in[12];
    const float* t_var   = (const float*)d_in[13];
    const float* tw2     = (const float*)d_in[14];
    const float* tb2     = (const float*)d_in[15];

    float* ws   = (float*)d_ws;
    float* outp = (float*)d_out;
    const int B = in_sizes[0] / 128;   // 262144

    tarnet_pre<<<1, 256, 0, stream>>>(fw, fb, f_gamma, f_beta, f_mean, f_var,
                                      tw1, tb1, t_gamma, t_beta, t_mean, t_var,
                                      tw2, tb2, ws);
    tarnet_main<<<B / 256, 256, 0, stream>>>(x, t, ws, outp);
}

// Round 8
// 56.042 us; speedup vs baseline: 1.2800x; 1.1269x over previous
//
#include <hip/hip_runtime.h>
#include <hip/hip_bf16.h>
#include <cstdint>

#define EPS 1e-5f

typedef short bf16x8 __attribute__((ext_vector_type(8)));
typedef float f32x16 __attribute__((ext_vector_type(16)));
typedef unsigned int u32x4 __attribute__((ext_vector_type(4)));

// ws float-offsets
#define WS_TW1S 0       // 16384 ushort: chi-permuted GEMM2 A-frag layout
#define WS_FWQ  8192    // 8192 ushort: GEMM1 A-frag layout [((ks*2+h)*64 + hc)*8 + jj]
#define WS_TB1Q 12288   // 256 floats: [(t*2+hi)*16 + q]
#define WS_W2Q  12544   // 256 floats: [(t*2+hi)*16 + q]
#define WS_FBQ  12800   // 64 floats:  [hi*32 + ht*16 + q]
#define WS_C2   12864   // 8 floats

static __device__ __forceinline__ unsigned short f2bf(float f) {
    unsigned int u = __float_as_uint(f);
    u += 0x7fffu + ((u >> 16) & 1u);   // RNE
    return (unsigned short)(u >> 16);
}
static __device__ __forceinline__ short f2bf_fast(float f) {
    __hip_bfloat16 b = __float2bfloat16(f);
    return __builtin_bit_cast(short, b);
}
static __device__ __forceinline__ unsigned pk_bf16(float lo, float hi) {
    unsigned l = (unsigned)(unsigned short)__builtin_bit_cast(unsigned short, __float2bfloat16(lo));
    unsigned h = (unsigned)(unsigned short)__builtin_bit_cast(unsigned short, __float2bfloat16(hi));
    return l | (h << 16);
}

// Fold both eval-mode BNs; emit bf16 weights in frag-native layouts.
// chi: channel j = ht*32+qq*8+4h+m -> ks = ht*2+(qq>>1), slot = 8h+(qq&1)*4+m
__global__ void tarnet_pre(
    const float* __restrict__ fw, const float* __restrict__ fb,
    const float* __restrict__ f_gamma, const float* __restrict__ f_beta,
    const float* __restrict__ f_mean,  const float* __restrict__ f_var,
    const float* __restrict__ tw1, const float* __restrict__ tb1,
    const float* __restrict__ t_gamma, const float* __restrict__ t_beta,
    const float* __restrict__ t_mean,  const float* __restrict__ t_var,
    const float* __restrict__ tw2, const float* __restrict__ tb2,
    float* __restrict__ ws)
{
    __shared__ float fs[64], fsh[64];
    const int i = threadIdx.x;  // 256 threads
    if (i < 64) {
        float s = f_gamma[i] * rsqrtf(f_var[i] + EPS);
        fs[i]  = s;
        fsh[i] = f_beta[i] - f_mean[i] * s;
    }
    __syncthreads();

    unsigned short* tw1s_u = (unsigned short*)(ws + WS_TW1S);
    unsigned short* fwq_u  = (unsigned short*)(ws + WS_FWQ);

    const int t = i >> 5, r = i & 31;
    const int idx = t * 32 + r;
    {
        float tsc  = t_gamma[idx] * rsqrtf(t_var[idx] + EPS);
        float w2s  = tw2[idx] * tsc;
        float tb1s = tb1[idx];
        for (int j = 0; j < 64; ++j) {
            float w = tw1[idx * 64 + j];
            tb1s += w * fsh[j];
            int ht = j >> 5, qq = (j >> 3) & 3, h = (j >> 2) & 1, m = j & 3;
            int ks = ht * 2 + (qq >> 1);
            int ep = (qq & 1) * 4 + m;
            tw1s_u[(((t*4 + ks)*2 + h)*32 + r)*8 + ep] = f2bf(w * fs[j]);
        }
        int q  = ((r >> 3) << 2) | (r & 3);
        int hq = (r >> 2) & 1;
        ws[WS_TB1Q + (t*2 + hq)*16 + q] = tb1s;
        ws[WS_W2Q  + (t*2 + hq)*16 + q] = w2s;
    }
    if (r == 0) {
        float a = tb2[t];
        for (int rr = 0; rr < 32; ++rr) {
            int id2 = t*32 + rr;
            float ts2 = t_gamma[id2] * rsqrtf(t_var[id2] + EPS);
            a += tw2[id2] * (t_beta[id2] - ts2 * t_mean[id2]);
        }
        ws[WS_C2 + t] = a;
    }
    if (i < 64) {  // i = hc: GEMM1 A-frag layout
        for (int k = 0; k < 128; ++k) {
            int ks = k >> 4, h = (k >> 3) & 1, jj = k & 7;
            fwq_u[(((ks*2 + h)*64) + i)*8 + jj] = f2bf(fw[i*128 + k]);
        }
        int ht = i >> 5, r32 = i & 31;
        int q  = ((r32 >> 3) << 2) | (r32 & 3);
        int hq = (r32 >> 2) & 1;
        ws[WS_FBQ + hq*32 + ht*16 + q] = fb[i];
    }
}

// 4 waves/block, 256 samples/block. x coalesced-staged into swizzled bf16 LDS.
__global__ __launch_bounds__(256, 2) void tarnet_main(
    const float* __restrict__ x, const int* __restrict__ t_arr,
    const float* __restrict__ ws, float* __restrict__ out)
{
    __shared__ unsigned short x_lds_u[256 * 128];   // 64 KB bf16, XOR-swizzled
    char* xl = (char*)x_lds_u;

    const int tid  = threadIdx.x;
    const int wave = tid >> 6, lane = tid & 63;
    const int ln31 = lane & 31, hi = lane >> 5;
    const int sbase = blockIdx.x * 256;

    // ---- coalesced staging: 16 iters x (2 adjacent dwordx4 = 32B/lane contiguous) ----
    // pair index i -> row = i>>4, 16B-col = i&15; swizzle XORs byte bits 4-7 with row&15
    {
        const float4* xg = (const float4*)(x + (size_t)sbase * 128);
#pragma unroll
        for (int it = 0; it < 16; ++it) {
            const int i = it * 256 + tid;
            float4 a = xg[2*i], b = xg[2*i + 1];
            bf16x8 v;
            v[0] = f2bf_fast(a.x); v[1] = f2bf_fast(a.y);
            v[2] = f2bf_fast(a.z); v[3] = f2bf_fast(a.w);
            v[4] = f2bf_fast(b.x); v[5] = f2bf_fast(b.y);
            v[6] = f2bf_fast(b.z); v[7] = f2bf_fast(b.w);
            const int row = i >> 4, pcol = i & 15;
            const int addr = row * 256 + ((pcol * 16) ^ ((row & 15) << 4));
            *(bf16x8*)(xl + addr) = v;
        }
    }
    __syncthreads();

    const unsigned short* fwq_u  = (const unsigned short*)(ws + WS_FWQ);
    const unsigned short* tw1s_u = (const unsigned short*)(ws + WS_TW1S);

    const int tsel0 = t_arr[sbase + wave * 64 + ln31];
    const int tsel1 = t_arr[sbase + wave * 64 + 32 + ln31];

    // this lane's two sample rows in LDS
    const int srow0 = wave * 64 + ln31;
    const int srow1 = srow0 + 32;
    const int rb0 = srow0 * 256, xr0 = (srow0 & 15) << 4;
    const int rb1 = srow1 * 256, xr1 = (srow1 & 15) << 4;

    // ---- GEMM1: h^T = fw @ x^T (+fb), rows=hc, cols=samples ----
    f32x16 acc[2][2];   // [st][ht]
    {
        const float* fbq = ws + WS_FBQ;
#pragma unroll
        for (int ht = 0; ht < 2; ++ht)
#pragma unroll
            for (int q = 0; q < 16; ++q) {
                float v = fbq[hi*32 + ht*16 + q];
                acc[0][ht][q] = v;
                acc[1][ht][q] = v;
            }
    }
#pragma unroll
    for (int ks = 0; ks < 8; ++ks) {
        // A-frags from global (L1-hot, lane-consecutive 16B)
        bf16x8 wa0 = *(const bf16x8*)(fwq_u + (((ks*2 + hi)*64) + ln31     )*8);
        bf16x8 wa1 = *(const bf16x8*)(fwq_u + (((ks*2 + hi)*64) + ln31 + 32)*8);
        // B-frags from swizzled LDS
        const int c = ks*32 + hi*16;
        bf16x8 xf0 = *(const bf16x8*)(xl + rb0 + (c ^ xr0));
        bf16x8 xf1 = *(const bf16x8*)(xl + rb1 + (c ^ xr1));
        acc[0][0] = __builtin_amdgcn_mfma_f32_32x32x16_bf16(wa0, xf0, acc[0][0], 0, 0, 0);
        acc[0][1] = __builtin_amdgcn_mfma_f32_32x32x16_bf16(wa1, xf0, acc[0][1], 0, 0, 0);
        acc[1][0] = __builtin_amdgcn_mfma_f32_32x32x16_bf16(wa0, xf1, acc[1][0], 0, 0, 0);
        acc[1][1] = __builtin_amdgcn_mfma_f32_32x32x16_bf16(wa1, xf1, acc[1][1], 0, 0, 0);
    }

    // ---- relu -> bf16 pack: lane-local B-frags under chi ----
    bf16x8 hb[2][4];   // [st][ks]
#pragma unroll
    for (int st = 0; st < 2; ++st) {
        unsigned w0[2][4], w1[2][4];
#pragma unroll
        for (int ht = 0; ht < 2; ++ht)
#pragma unroll
            for (int qq = 0; qq < 4; ++qq) {
                float a0 = fmaxf(acc[st][ht][qq*4+0], 0.f);
                float a1 = fmaxf(acc[st][ht][qq*4+1], 0.f);
                float a2 = fmaxf(acc[st][ht][qq*4+2], 0.f);
                float a3 = fmaxf(acc[st][ht][qq*4+3], 0.f);
                w0[ht][qq] = pk_bf16(a0, a1);
                w1[ht][qq] = pk_bf16(a2, a3);
            }
#pragma unroll
        for (int ks = 0; ks < 4; ++ks) {
            const int ht = ks >> 1, qa = (ks & 1) * 2;
            u32x4 wv = {w0[ht][qa], w1[ht][qa], w0[ht][qa+1], w1[ht][qa+1]};
            hb[st][ks] = __builtin_bit_cast(bf16x8, wv);
        }
    }

    // ---- GEMM2 dense over 8 heads: z = tw1s[th] @ h, rows=r, cols=samples ----
    float out0 = 0.f, out1 = 0.f;
#pragma unroll 2
    for (int th = 0; th < 8; ++th) {
        bf16x8 aw[4];
#pragma unroll
        for (int ks = 0; ks < 4; ++ks)
            aw[ks] = *(const bf16x8*)(tw1s_u + (((th*4 + ks)*2 + hi)*32 + ln31)*8);
        float4 tb4[4], w24[4];
#pragma unroll
        for (int i2 = 0; i2 < 4; ++i2) {
            tb4[i2] = ((const float4*)(ws + WS_TB1Q))[(th*2 + hi)*4 + i2];
            w24[i2] = ((const float4*)(ws + WS_W2Q))[(th*2 + hi)*4 + i2];
        }
        const float c2t = ws[WS_C2 + th];
#pragma unroll
        for (int st = 0; st < 2; ++st) {
            f32x16 z;
#pragma unroll
            for (int q = 0; q < 16; ++q) z[q] = ((const float*)tb4)[q];  // tb1s C-init
            z = __builtin_amdgcn_mfma_f32_32x32x16_bf16(aw[0], hb[st][0], z, 0, 0, 0);
            z = __builtin_amdgcn_mfma_f32_32x32x16_bf16(aw[1], hb[st][1], z, 0, 0, 0);
            z = __builtin_amdgcn_mfma_f32_32x32x16_bf16(aw[2], hb[st][2], z, 0, 0, 0);
            z = __builtin_amdgcn_mfma_f32_32x32x16_bf16(aw[3], hb[st][3], z, 0, 0, 0);
            float p0 = 0.f, p1 = 0.f, p2 = 0.f, p3 = 0.f;
#pragma unroll
            for (int q = 0; q < 4; ++q) {
                p0 = fmaf(((const float*)w24)[q],    fmaxf(z[q],    0.f), p0);
                p1 = fmaf(((const float*)w24)[q+4],  fmaxf(z[q+4],  0.f), p1);
                p2 = fmaf(((const float*)w24)[q+8],  fmaxf(z[q+8],  0.f), p2);
                p3 = fmaf(((const float*)w24)[q+12], fmaxf(z[q+12], 0.f), p3);
            }
            float p = (p0 + p1) + (p2 + p3);
            p += __shfl_xor(p, 32);   // other r-half
            p += c2t;
            if (st == 0) out0 = (th == tsel0) ? p : out0;
            else         out1 = (th == tsel1) ? p : out1;
        }
    }
    out[sbase + wave * 64 + lane] = hi ? out1 : out0;   // coalesced 64-lane store
}

extern "C" void kernel_launch(void* const* d_in, const int* in_sizes, int n_in,
                              void* d_out, int out_size, void* d_ws, size_t ws_size,
                              hipStream_t stream) {
    const float* x       = (const float*)d_in[0];
    const int*   t       = (const int*)  d_in[1];
    const float* fw      = (const float*)d_in[2];
    const float* fb      = (const float*)d_in[3];
    const float* f_gamma = (const float*)d_in[4];
    const float* f_beta  = (const float*)d_in[5];
    const float* f_mean  = (const float*)d_in[6];
    const float* f_var   = (const float*)d_in[7];
    const float* tw1     = (const float*)d_in[8];
    const float* tb1     = (const float*)d_in[9];
    const float* t_gamma = (const float*)d_in[10];
    const float* t_beta  = (const float*)d_in[11];
    const float* t_mean  = (const float*)d_in[12];
    const float* t_var   = (const float*)d_in[13];
    const float* tw2     = (const float*)d_in[14];
    const float* tb2     = (const float*)d_in[15];

    float* ws   = (float*)d_ws;
    float* outp = (float*)d_out;
    const int B = in_sizes[0] / 128;   // 262144

    tarnet_pre<<<1, 256, 0, stream>>>(fw, fb, f_gamma, f_beta, f_mean, f_var,
                                      tw1, tb1, t_gamma, t_beta, t_mean, t_var,
                                      tw2, tb2, ws);
    tarnet_main<<<B / 256, 256, 0, stream>>>(x, t, ws, outp);
}